// Round 13
// baseline (142.169 us; speedup 1.0000x reference)
//
#include <hip/hip_runtime.h>
#include <hip/hip_bf16.h>
#include <cstdint>
#include <cstddef>

#define B_ 16
#define N_ 2048
#define L_ 12
#define C_ 32
#define KTOP 1638
#define SCALE 0.17677669529663687f   // 1/sqrt(32)
#define LOG2E 1.44269504088896f

typedef __attribute__((ext_vector_type(8))) short short8v;
typedef __attribute__((ext_vector_type(4))) float f32x4;

#if __has_builtin(__builtin_amdgcn_exp2f)
#define EXP2F(x) __builtin_amdgcn_exp2f(x)
#else
#define EXP2F(x) exp2f(x)
#endif

__device__ __forceinline__ unsigned short bf16_rne(float v) {
  unsigned u = __float_as_uint(v);
  u += 0x7FFFu + ((u >> 16) & 1u);
  return (unsigned short)(u >> 16);
}
// exp(x) quartic for x in [0, 0.72]: abs err <= ~1.6e-3 (x^5/120)
__device__ __forceinline__ float exp_poly4(float x) {
  return fmaf(x, fmaf(x, fmaf(x, fmaf(x, 0.041666667f, 0.166666667f), 0.5f), 1.f), 1.f);
}

// Kernel 1: xsum split into bf16 hi/lo, layout [b][n][c]; blocks with b==0
// also convert mem (f32 [c][m]) -> bf16 memT [m][c] (batch-invariant).
__global__ __launch_bounds__(256) void prep_kernel(const float* __restrict__ x,
                                                   const float* __restrict__ mem,
                                                   unsigned short* __restrict__ xsH,
                                                   unsigned short* __restrict__ xsL,
                                                   unsigned short* __restrict__ memT) {
  const int b = blockIdx.y, n0 = blockIdx.x * 64;
  const int c = threadIdx.x & 31, nr = threadIdx.x >> 5;
#pragma unroll
  for (int i = 0; i < 8; ++i) {
    const int n = n0 + i * 8 + nr;
    const float* px = x + ((size_t)(b * N_ + n) * L_) * C_ + c;
    float s = 0.f;
#pragma unroll
    for (int l = 0; l < L_; ++l) s += px[l * C_];
    const unsigned short h = bf16_rne(s);
    const float hf = __uint_as_float((unsigned)h << 16);
    const unsigned short lo = bf16_rne(s - hf);
    const size_t o = (size_t)(b * N_ + n) * C_ + c;
    xsH[o] = h;
    xsL[o] = lo;
  }
  if (b == 0) {
#pragma unroll
    for (int i = 0; i < 8; ++i) {
      const int idx = i * 256 + threadIdx.x;
      const int ml = idx >> 5, cc = idx & 31;
      memT[(size_t)(n0 + ml) * C_ + cc] = bf16_rne(mem[(size_t)cc * N_ + n0 + ml]);
    }
  }
}

// Kernel 2: one block = 8 rows, 512 threads (8 waves). REGISTER-RESIDENT
// phase B: each lane keeps its MFMA outputs (2 rows x 16 cols, p1/p2 packed)
// in registers; cross-wave aggregation (S1/S2, counts, exp-sums) via 8x8 LDS
// tables. pbuf (64 KB) is declared (occupancy same as R12: 2 blocks/CU) but
// only touched by the never-taken fallback, which rebuilds p via a fresh MFMA
// loop and runs the R12 per-wave bf16-key search.
__global__ __launch_bounds__(512, 4) void adj_kernel(
    const unsigned short* __restrict__ xsH, const unsigned short* __restrict__ xsL,
    const unsigned short* __restrict__ memT, const float* __restrict__ fc_w,
    const float* __restrict__ fc_b, float* __restrict__ out) {
  __shared__ unsigned pbuf[8][2049];            // fallback-only staging
  __shared__ float red1[8][8], red2[8][8];      // S1,S2 [row][wave]
  __shared__ unsigned redC[8][8];               // packed counts [row][wave]
  __shared__ float redE[8][8];                  // exp-sums [row][wave]

  const int tid = threadIdx.x, wid = tid >> 6, lane = tid & 63;
  const int l15 = lane & 15, g = lane >> 4;
  const int b = blockIdx.y, n0 = blockIdx.x * 8;

  // Permuted A rows: lane group g's C components {0,1} are logical rows
  // {rbase, rbase+1}, rbase = {0,4,2,6}[g].
  const int fr = (l15 < 8) ? l15 : ((l15 - 6) & 7);
  const int rbase = (g & 1) * 4 + (g & 2);
  const int g8 = g * 8;
  const size_t arow = (size_t)(b * N_ + n0 + fr) * C_ + g8;
  const short8v hiA = *(const short8v*)(xsH + arow);
  const short8v loFA = *(const short8v*)(xsL + arow);

  const f32x4 zero = {0.f, 0.f, 0.f, 0.f};
  const float K = SCALE * LOG2E;
  const float C2 = -80.f * LOG2E;
  const int mbase = wid * 256 + l15;
  const size_t bcol = (size_t)b * N_ * C_ + (size_t)mbase * C_ + g8;
  const unsigned short* pH = xsH + bcol;
  const unsigned short* pL = xsL + bcol;
  const unsigned short* pM = memT + (size_t)mbase * C_ + g8;

  float s1[2] = {0.f, 0.f}, s2[2] = {0.f, 0.f};
  unsigned pA[16], pB[16];   // packed (bf16 p2 << 16) | bf16 p1, rows rbase / rbase+1

#pragma unroll
  for (int t = 0; t < 16; ++t) {
    const short8v hiB = *(const short8v*)(pH + t * (16 * C_));
    const short8v loB = *(const short8v*)(pL + t * (16 * C_));
    const short8v mB  = *(const short8v*)(pM + t * (16 * C_));

    f32x4 acc1 = __builtin_amdgcn_mfma_f32_16x16x32_bf16(hiA, mB, zero, 0, 0, 0);
    f32x4 acc2 = __builtin_amdgcn_mfma_f32_16x16x32_bf16(hiA, hiB, zero, 0, 0, 0);
    acc2 = __builtin_amdgcn_mfma_f32_16x16x32_bf16(hiA, loB, acc2, 0, 0, 0);
    acc2 = __builtin_amdgcn_mfma_f32_16x16x32_bf16(loFA, hiB, acc2, 0, 0, 0);

    {
      const float p1 = EXP2F(fmaxf(acc1[0], 0.f) * K);
      const float p2 = EXP2F(fminf(fmaf(fmaxf(acc2[0], 0.f), K, C2), 127.f));
      s1[0] += p1; s2[0] += p2;
      union { __hip_bfloat162 h2; unsigned u; } pk;
      pk.h2 = __float22bfloat162_rn(float2{p1, p2});
      pA[t] = pk.u;
    }
    {
      const float p1 = EXP2F(fmaxf(acc1[1], 0.f) * K);
      const float p2 = EXP2F(fminf(fmaf(fmaxf(acc2[1], 0.f), K, C2), 127.f));
      s1[1] += p1; s2[1] += p2;
      union { __hip_bfloat162 h2; unsigned u; } pk;
      pk.h2 = __float22bfloat162_rn(float2{p1, p2});
      pB[t] = pk.u;
    }
  }

  // ---- S1/S2: 16-lane group reduce + 8x8 table ----
#pragma unroll
  for (int d = 1; d < 16; d <<= 1) {
#pragma unroll
    for (int s = 0; s < 2; ++s) {
      s1[s] += __shfl_xor(s1[s], d);
      s2[s] += __shfl_xor(s2[s], d);
    }
  }
  if (l15 == 0) {
    red1[rbase][wid] = s1[0]; red1[rbase + 1][wid] = s1[1];
    red2[rbase][wid] = s2[0]; red2[rbase + 1][wid] = s2[1];
  }
  __syncthreads();
  float S1A = 0.f, S1B = 0.f, S2A = 0.f, S2B = 0.f;
#pragma unroll
  for (int w = 0; w < 8; ++w) {
    S1A += red1[rbase][w]; S1B += red1[rbase + 1][w];
    S2A += red2[rbase][w]; S2B += red2[rbase + 1][w];
  }
  const float w0 = fc_w[0], w1 = fc_w[1], bb = fc_b[0];
  const float i1A = w0 / S1A, i2A = w1 / S2A;
  const float i1B = w0 / S1B, i2B = w1 / S2B;

  // Tie values (bit-exact vs per-element adj below; p2 is bf16-rounded in pA).
  const float p2t = __uint_as_float((unsigned)bf16_rne(EXP2F(C2)) << 16);
  const float TA = fmaf(p2t, i2A, fmaf(1.0f, i1A, bb));
  const float TB = fmaf(p2t, i2B, fmaf(1.0f, i1B, bb));

  // ---- fused optimistic pass: adj, counts, masked poly-exp, pack (in place) ----
  unsigned cntA = 0, cntB = 0;
  float ssA = 0.f, ssB = 0.f;
#pragma unroll
  for (int t = 0; t < 16; ++t) {
    const unsigned qa = pA[t], qb = pB[t];
    const float adjA = fmaf(__uint_as_float(qa & 0xFFFF0000u), i2A,
                      fmaf(__uint_as_float(qa << 16), i1A, bb));
    const float adjB = fmaf(__uint_as_float(qb & 0xFFFF0000u), i2B,
                      fmaf(__uint_as_float(qb << 16), i1B, bb));
    cntA += ((adjA >= TA) ? 1u : 0u) + ((adjA > TA) ? 0x10000u : 0u);
    cntB += ((adjB >= TB) ? 1u : 0u) + ((adjB > TB) ? 0x10000u : 0u);
    const float eA = exp_poly4((adjA >= TA) ? adjA : 0.f);
    const float eB = exp_poly4((adjB >= TB) ? adjB : 0.f);
    ssA += eA; ssB += eB;
    union { __hip_bfloat162 h2; unsigned u; } pk;
    pk.h2 = __float22bfloat162_rn(float2{eA, eB});
    pA[t] = pk.u;                       // overwrite: pA becomes packed exp
  }

  // ---- reduce counts + exp-sums: group shfl + tables ----
#pragma unroll
  for (int d = 1; d < 16; d <<= 1) {
    cntA += (unsigned)__shfl_xor((int)cntA, d);
    cntB += (unsigned)__shfl_xor((int)cntB, d);
    ssA += __shfl_xor(ssA, d);
    ssB += __shfl_xor(ssB, d);
  }
  if (l15 == 0) {
    redC[rbase][wid] = cntA; redC[rbase + 1][wid] = cntB;
    redE[rbase][wid] = ssA;  redE[rbase + 1][wid] = ssB;
  }
  __syncthreads();
  unsigned CA = 0, CB = 0;
  float SEA = 0.f, SEB = 0.f;
#pragma unroll
  for (int w = 0; w < 8; ++w) {
    CA += redC[rbase][w]; CB += redC[rbase + 1][w];
    SEA += redE[rbase][w]; SEB += redE[rbase + 1][w];
  }
  const bool okA = ((CA & 0xFFFFu) >= KTOP) && ((CA >> 16) < KTOP);
  const bool okB = ((CB & 0xFFFFu) >= KTOP) && ((CB >> 16) < KTOP);

  if (__all(okA && okB)) {
    // ---- fast path (expected always): scale + store from registers ----
    const float invA = 1.f / SEA, invB = 1.f / SEB;
    float* opA = out + ((size_t)(b * N_ + n0 + rbase)) * N_ + mbase;
    float* opB = opA + N_;
#pragma unroll
    for (int t = 0; t < 16; ++t) {
      opA[t * 16] = __uint_as_float(pA[t] << 16) * invA;
      opB[t * 16] = __uint_as_float(pA[t] & 0xFFFF0000u) * invB;
    }
  } else {
    // ---- rare fallback: rebuild p into pbuf (fresh MFMA loop), then R12's
    // per-wave bf16-key binary search + store. Block-uniform branch. ----
    unsigned* pw = &pbuf[rbase][mbase];
#pragma unroll 2
    for (int t = 0; t < 16; ++t) {
      const short8v hiB = *(const short8v*)(pH + t * (16 * C_));
      const short8v loB = *(const short8v*)(pL + t * (16 * C_));
      const short8v mB  = *(const short8v*)(pM + t * (16 * C_));
      f32x4 acc1 = __builtin_amdgcn_mfma_f32_16x16x32_bf16(hiA, mB, zero, 0, 0, 0);
      f32x4 acc2 = __builtin_amdgcn_mfma_f32_16x16x32_bf16(hiA, hiB, zero, 0, 0, 0);
      acc2 = __builtin_amdgcn_mfma_f32_16x16x32_bf16(hiA, loB, acc2, 0, 0, 0);
      acc2 = __builtin_amdgcn_mfma_f32_16x16x32_bf16(loFA, hiB, acc2, 0, 0, 0);
#pragma unroll
      for (int s = 0; s < 2; ++s) {
        const float p1 = EXP2F(fmaxf(acc1[s], 0.f) * K);
        const float p2 = EXP2F(fminf(fmaf(fmaxf(acc2[s], 0.f), K, C2), 127.f));
        union { __hip_bfloat162 h2; unsigned u; } pk;
        pk.h2 = __float22bfloat162_rn(float2{p1, p2});
        pw[s * 2049 + t * 16] = pk.u;
      }
    }
    __syncthreads();

    const int r = wid;
    float S1w = 0.f, S2w = 0.f;
#pragma unroll
    for (int w = 0; w < 8; ++w) { S1w += red1[r][w]; S2w += red2[r][w]; }
    const float i1 = w0 / S1w, i2 = w1 / S2w;
    const unsigned* prow = &pbuf[0][0] + r * 2049;

    unsigned pk2[16], kg[16];
#pragma unroll
    for (int k = 0; k < 8; ++k) {
      const uint4 q = *(const uint4*)&prow[4 * lane + 256 * k];
      const unsigned qq[4] = {q.x, q.y, q.z, q.w};
      float a4[4];
#pragma unroll
      for (int c4 = 0; c4 < 4; ++c4) {
        const float p1 = __uint_as_float(qq[c4] << 16);
        const float p2 = __uint_as_float(qq[c4] & 0xFFFF0000u);
        a4[c4] = fmaf(p2, i2, fmaf(p1, i1, bb));
      }
      union { __hip_bfloat162 h2; unsigned u; } cA2, cB2;
      cA2.h2 = __float22bfloat162_rn(float2{a4[0], a4[1]});
      cB2.h2 = __float22bfloat162_rn(float2{a4[2], a4[3]});
      pk2[2 * k] = cA2.u; pk2[2 * k + 1] = cB2.u;
      unsigned sgn = (cA2.u >> 15) & 0x00010001u;
      unsigned srt = cA2.u ^ 0x80008000u ^ (sgn * 0x7FFFu);
      kg[2 * k] = ((srt >> 1) & 0x7FFF7FFFu) | 0x80008000u;
      sgn = (cB2.u >> 15) & 0x00010001u;
      srt = cB2.u ^ 0x80008000u ^ (sgn * 0x7FFFu);
      kg[2 * k + 1] = ((srt >> 1) & 0x7FFF7FFFu) | 0x80008000u;
    }
    unsigned mn = 0x7FFFu, mx = 0u;
#pragma unroll
    for (int j = 0; j < 16; ++j) {
      const unsigned k15 = kg[j] & 0x7FFF7FFFu;
      mn = min(mn, min(k15 & 0xFFFFu, k15 >> 16));
      mx = max(mx, max(k15 & 0xFFFFu, k15 >> 16));
    }
#pragma unroll
    for (int d = 1; d < 64; d <<= 1) {
      mn = min(mn, (unsigned)__shfl_xor((int)mn, d));
      mx = max(mx, (unsigned)__shfl_xor((int)mx, d));
    }
    unsigned lo2 = mn, hi2 = mx;
#pragma unroll 1
    for (int it = 0; it < 15; ++it) {
      if (lo2 >= hi2) break;
      const unsigned mid = (lo2 + hi2 + 1u) >> 1;
      const unsigned mm = mid * 0x10001u;
      unsigned c0 = 0;
#pragma unroll
      for (int j = 0; j < 16; ++j) c0 += ((kg[j] - mm) >> 15) & 0x10001u;
      unsigned cnt = (c0 & 0xFFFFu) + (c0 >> 16);
#pragma unroll
      for (int d = 1; d < 64; d <<= 1) cnt += (unsigned)__shfl_xor((int)cnt, d);
      if (cnt >= KTOP) lo2 = mid; else hi2 = mid - 1u;
    }
    const unsigned lolo = lo2 * 0x10001u;
    float s2sum = 0.f;
    float exf[32];
#pragma unroll
    for (int j = 0; j < 16; ++j) {
      const unsigned ge = kg[j] - lolo;
      const float aA = (ge & 0x8000u) ? __uint_as_float(pk2[j] << 16) : 0.f;
      const float aB = (ge & 0x80000000u) ? __uint_as_float(pk2[j] & 0xFFFF0000u) : 0.f;
      const float eA = EXP2F(aA * LOG2E);
      const float eB = EXP2F(aB * LOG2E);
      exf[2 * j] = eA; exf[2 * j + 1] = eB;
      s2sum += eA + eB;
    }
#pragma unroll
    for (int d = 1; d < 64; d <<= 1) s2sum += __shfl_xor(s2sum, d);
    const float inv = 1.f / s2sum;
    float* op = out + ((size_t)(b * N_ + n0 + r)) * N_;
#pragma unroll
    for (int k = 0; k < 8; ++k) {
      float4 o;
      o.x = exf[4 * k + 0] * inv; o.y = exf[4 * k + 1] * inv;
      o.z = exf[4 * k + 2] * inv; o.w = exf[4 * k + 3] * inv;
      *(float4*)(op + 4 * lane + 256 * k) = o;
    }
  }
}

extern "C" void kernel_launch(void* const* d_in, const int* in_sizes, int n_in,
                              void* d_out, int out_size, void* d_ws, size_t ws_size,
                              hipStream_t stream) {
  const float* x   = (const float*)d_in[0];
  const float* mem = (const float*)d_in[1];
  const float* fcw = (const float*)d_in[2];
  const float* fcb = (const float*)d_in[3];
  float* out = (float*)d_out;
  unsigned short* xsH  = (unsigned short*)d_ws;             // 2 MB
  unsigned short* xsL  = xsH + (size_t)B_ * N_ * C_;        // 2 MB
  unsigned short* memT = xsL + (size_t)B_ * N_ * C_;        // 128 KB

  dim3 g1(N_ / 64, B_);
  prep_kernel<<<g1, 256, 0, stream>>>(x, mem, xsH, xsL, memT);
  dim3 g2(N_ / 8, B_);
  adj_kernel<<<g2, 512, 0, stream>>>(xsH, xsL, memT, fcw, fcb, out);
}

// Round 14
// 136.117 us; speedup vs baseline: 1.0445x; 1.0445x over previous
//
#include <hip/hip_runtime.h>
#include <hip/hip_bf16.h>
#include <cstdint>
#include <cstddef>

#define B_ 16
#define N_ 2048
#define L_ 12
#define C_ 32
#define KTOP 1638
#define SCALE 0.17677669529663687f   // 1/sqrt(32)
#define LOG2E 1.44269504088896f
#define PITCH 2064                    // u32 pitch: 2064%32==16 -> 2-way (free) ds_write

typedef __attribute__((ext_vector_type(8))) short short8v;
typedef __attribute__((ext_vector_type(4))) float f32x4;

#if __has_builtin(__builtin_amdgcn_exp2f)
#define EXP2F(x) __builtin_amdgcn_exp2f(x)
#else
#define EXP2F(x) exp2f(x)
#endif

__device__ __forceinline__ unsigned short bf16_rne(float v) {
  unsigned u = __float_as_uint(v);
  u += 0x7FFFu + ((u >> 16) & 1u);
  return (unsigned short)(u >> 16);
}
// exp(x) quartic for x in [0, 0.72]: abs err <= ~1.6e-3 (x^5/120)
__device__ __forceinline__ float exp_poly4(float x) {
  return fmaf(x, fmaf(x, fmaf(x, fmaf(x, 0.041666667f, 0.166666667f), 0.5f), 1.f), 1.f);
}

// Kernel 1: xsum split into bf16 hi/lo, layout [b][n][c]; blocks with b==0
// also convert mem -> bf16 memT [m][c], PRE-SCALED by K=SCALE*LOG2E so
// phase A computes p1 = exp2(max(acc1,0)) directly.
__global__ __launch_bounds__(256) void prep_kernel(const float* __restrict__ x,
                                                   const float* __restrict__ mem,
                                                   unsigned short* __restrict__ xsH,
                                                   unsigned short* __restrict__ xsL,
                                                   unsigned short* __restrict__ memT) {
  const int b = blockIdx.y, n0 = blockIdx.x * 64;
  const int c = threadIdx.x & 31, nr = threadIdx.x >> 5;
#pragma unroll
  for (int i = 0; i < 8; ++i) {
    const int n = n0 + i * 8 + nr;
    const float* px = x + ((size_t)(b * N_ + n) * L_) * C_ + c;
    float s = 0.f;
#pragma unroll
    for (int l = 0; l < L_; ++l) s += px[l * C_];
    const unsigned short h = bf16_rne(s);
    const float hf = __uint_as_float((unsigned)h << 16);
    const unsigned short lo = bf16_rne(s - hf);
    const size_t o = (size_t)(b * N_ + n) * C_ + c;
    xsH[o] = h;
    xsL[o] = lo;
  }
  if (b == 0) {
    const float KF = SCALE * LOG2E;
#pragma unroll
    for (int i = 0; i < 8; ++i) {
      const int idx = i * 256 + threadIdx.x;
      const int ml = idx >> 5, cc = idx & 31;
      memT[(size_t)(n0 + ml) * C_ + cc] = bf16_rne(mem[(size_t)cc * N_ + n0 + ml] * KF);
    }
  }
}

// Kernel 2: one block = 16 REAL rows, 1024 threads (16 waves). All 16 MFMA
// M-rows are real (no duplicate padding): half the MFMA + half the B-panel
// L2 traffic of the 8-row version. Phase A: MFMA + max-free softmaxes,
// p1/p2 cvt_pk'd to pbuf[16][PITCH]. Phase B: R12's per-wave f32-native
// fused pass (wave wid owns row wid) with tie-anchored fast path; fallback
// vote is BLOCK-uniform (LDS flags) before any divergent barrier.
__global__ __launch_bounds__(1024, 4) void adj_kernel(
    const unsigned short* __restrict__ xsH, const unsigned short* __restrict__ xsL,
    const unsigned short* __restrict__ memT, const float* __restrict__ fc_w,
    const float* __restrict__ fc_b, float* __restrict__ out) {
  __shared__ unsigned pbuf[16][PITCH];          // 132 KB staging
  __shared__ float red1[16][16], red2[16][16];  // S1,S2 [row][wave]
  __shared__ unsigned okfl[16];                 // per-wave fast-path flags

  const int tid = threadIdx.x, wid = tid >> 6, lane = tid & 63;
  const int l15 = lane & 15, g = lane >> 4;
  const int b = blockIdx.y, n0 = blockIdx.x * 16;

  // A fragment: row = l15 (all 16 real), channels g*8..g*8+7.
  const int g8 = g * 8;
  const size_t arow = (size_t)(b * N_ + n0 + l15) * C_ + g8;
  const short8v hiA = *(const short8v*)(xsH + arow);
  const short8v loFA = *(const short8v*)(xsL + arow);

  const f32x4 zero = {0.f, 0.f, 0.f, 0.f};
  const float K = SCALE * LOG2E;
  const float C2 = -80.f * LOG2E;
  const int mbase = wid * 128 + l15;            // 16 waves x 128-col stripes
  const size_t bcol = (size_t)b * N_ * C_ + (size_t)mbase * C_ + g8;
  const unsigned short* pH = xsH + bcol;
  const unsigned short* pL = xsL + bcol;
  const unsigned short* pM = memT + (size_t)mbase * C_ + g8;
  unsigned* pw = &pbuf[g * 4][mbase];

  float s1[4] = {0.f, 0.f, 0.f, 0.f}, s2[4] = {0.f, 0.f, 0.f, 0.f};

#pragma unroll
  for (int t = 0; t < 8; ++t) {
    const short8v hiB = *(const short8v*)(pH + t * (16 * C_));
    const short8v loB = *(const short8v*)(pL + t * (16 * C_));
    const short8v mB  = *(const short8v*)(pM + t * (16 * C_));

    f32x4 acc1 = __builtin_amdgcn_mfma_f32_16x16x32_bf16(hiA, mB, zero, 0, 0, 0);
    f32x4 acc2 = __builtin_amdgcn_mfma_f32_16x16x32_bf16(hiA, hiB, zero, 0, 0, 0);
    acc2 = __builtin_amdgcn_mfma_f32_16x16x32_bf16(hiA, loB, acc2, 0, 0, 0);
    acc2 = __builtin_amdgcn_mfma_f32_16x16x32_bf16(loFA, hiB, acc2, 0, 0, 0);

#pragma unroll
    for (int j = 0; j < 4; ++j) {
      const float p1 = EXP2F(fmaxf(acc1[j], 0.f));                       // memT pre-scaled
      const float p2 = EXP2F(fminf(fmaf(fmaxf(acc2[j], 0.f), K, C2), 127.f));
      s1[j] += p1; s2[j] += p2;
      union { __hip_bfloat162 h2; unsigned u; } pk;
      pk.h2 = __float22bfloat162_rn(float2{p1, p2});
      pw[j * PITCH + t * 16] = pk.u;
    }
  }

  // ---- S1/S2: 16-lane (col-group) reduce + [row][wave] table ----
#pragma unroll
  for (int d = 1; d < 16; d <<= 1) {
#pragma unroll
    for (int j = 0; j < 4; ++j) {
      s1[j] += __shfl_xor(s1[j], d);
      s2[j] += __shfl_xor(s2[j], d);
    }
  }
  if (l15 == 0) {
#pragma unroll
    for (int j = 0; j < 4; ++j) {
      red1[g * 4 + j][wid] = s1[j];
      red2[g * 4 + j][wid] = s2[j];
    }
  }
  __syncthreads();

  // ---- Phase B: wave wid owns row wid (full 2048 cols) ----
  const int r = wid;
  float S1 = 0.f, S2 = 0.f;
#pragma unroll
  for (int w = 0; w < 16; ++w) { S1 += red1[r][w]; S2 += red2[r][w]; }
  const float w0 = fc_w[0], w1 = fc_w[1], bb = fc_b[0];
  const float i1 = w0 / S1, i2 = w1 / S2;
  const unsigned* prow = &pbuf[0][0] + r * PITCH;

  // Tie value T, bit-exact vs per-element adj (tie: p1=1, p2=exp2(C2) rounded).
  const float p2t = __uint_as_float((unsigned)bf16_rne(EXP2F(C2)) << 16);
  const float T = fmaf(p2t, i2, fmaf(1.0f, i1, bb));

  unsigned exb[16];          // packed bf16 exp pairs
  float ssum = 0.f;
  unsigned cge = 0, cgt = 0;
#pragma unroll
  for (int k = 0; k < 8; ++k) {
    const uint4 q = *(const uint4*)&prow[4 * lane + 256 * k];
    const unsigned qq[4] = {q.x, q.y, q.z, q.w};
    float e4[4];
#pragma unroll
    for (int c4 = 0; c4 < 4; ++c4) {
      const float p1 = __uint_as_float(qq[c4] << 16);
      const float p2 = __uint_as_float(qq[c4] & 0xFFFF0000u);
      const float adj = fmaf(p2, i2, fmaf(p1, i1, bb));
      cge += (adj >= T) ? 1u : 0u;
      cgt += (adj >  T) ? 1u : 0u;
      const float e = exp_poly4((adj >= T) ? adj : 0.f);
      e4[c4] = e;
      ssum += e;
    }
    union { __hip_bfloat162 h2; unsigned u; } pa, pb2;
    pa.h2  = __float22bfloat162_rn(float2{e4[0], e4[1]});
    pb2.h2 = __float22bfloat162_rn(float2{e4[2], e4[3]});
    exb[2 * k] = pa.u; exb[2 * k + 1] = pb2.u;
  }
  unsigned comb = cge | (cgt << 16);
#pragma unroll
  for (int d = 1; d < 64; d <<= 1) {
    comb += (unsigned)__shfl_xor((int)comb, d);
    ssum += __shfl_xor(ssum, d);
  }
  const unsigned CGE = comb & 0xFFFFu, CGT = comb >> 16;
  const bool ok = (CGE >= KTOP) && (CGT < KTOP);

  // Block-uniform fallback vote (avoids divergent barrier UB).
  if (lane == 0) okfl[wid] = ok ? 1u : 0u;
  __syncthreads();
  unsigned allok = 1u;
#pragma unroll
  for (int w = 0; w < 16; ++w) allok &= okfl[w];

  float* op = out + ((size_t)(b * N_ + n0 + r)) * N_;

  if (allok) {
    // ---- fast path (expected always) ----
    const float inv = 1.f / ssum;
#pragma unroll
    for (int k = 0; k < 8; ++k) {
      float4 o;
      o.x = __uint_as_float(exb[2 * k] << 16) * inv;
      o.y = __uint_as_float(exb[2 * k] & 0xFFFF0000u) * inv;
      o.z = __uint_as_float(exb[2 * k + 1] << 16) * inv;
      o.w = __uint_as_float(exb[2 * k + 1] & 0xFFFF0000u) * inv;
      *(float4*)(op + 4 * lane + 256 * k) = o;
    }
  } else {
    // ---- rare fallback (block-uniform): bf16-key binary search on pbuf ----
    const float i1f = i1, i2f = i2;
    unsigned pk2[16], kg[16];
#pragma unroll
    for (int k = 0; k < 8; ++k) {
      const uint4 q = *(const uint4*)&prow[4 * lane + 256 * k];
      const unsigned qq[4] = {q.x, q.y, q.z, q.w};
      float a4[4];
#pragma unroll
      for (int c4 = 0; c4 < 4; ++c4) {
        const float p1 = __uint_as_float(qq[c4] << 16);
        const float p2 = __uint_as_float(qq[c4] & 0xFFFF0000u);
        a4[c4] = fmaf(p2, i2f, fmaf(p1, i1f, bb));
      }
      union { __hip_bfloat162 h2; unsigned u; } cA2, cB2;
      cA2.h2 = __float22bfloat162_rn(float2{a4[0], a4[1]});
      cB2.h2 = __float22bfloat162_rn(float2{a4[2], a4[3]});
      pk2[2 * k] = cA2.u; pk2[2 * k + 1] = cB2.u;
      unsigned sgn = (cA2.u >> 15) & 0x00010001u;
      unsigned srt = cA2.u ^ 0x80008000u ^ (sgn * 0x7FFFu);
      kg[2 * k] = ((srt >> 1) & 0x7FFF7FFFu) | 0x80008000u;
      sgn = (cB2.u >> 15) & 0x00010001u;
      srt = cB2.u ^ 0x80008000u ^ (sgn * 0x7FFFu);
      kg[2 * k + 1] = ((srt >> 1) & 0x7FFF7FFFu) | 0x80008000u;
    }
    unsigned mn = 0x7FFFu, mx = 0u;
#pragma unroll
    for (int j = 0; j < 16; ++j) {
      const unsigned k15 = kg[j] & 0x7FFF7FFFu;
      mn = min(mn, min(k15 & 0xFFFFu, k15 >> 16));
      mx = max(mx, max(k15 & 0xFFFFu, k15 >> 16));
    }
#pragma unroll
    for (int d = 1; d < 64; d <<= 1) {
      mn = min(mn, (unsigned)__shfl_xor((int)mn, d));
      mx = max(mx, (unsigned)__shfl_xor((int)mx, d));
    }
    unsigned lo2 = mn, hi2 = mx;
#pragma unroll 1
    for (int it = 0; it < 15; ++it) {
      if (lo2 >= hi2) break;
      const unsigned mid = (lo2 + hi2 + 1u) >> 1;
      const unsigned mm = mid * 0x10001u;
      unsigned c0 = 0;
#pragma unroll
      for (int j = 0; j < 16; ++j) c0 += ((kg[j] - mm) >> 15) & 0x10001u;
      unsigned cnt = (c0 & 0xFFFFu) + (c0 >> 16);
#pragma unroll
      for (int d = 1; d < 64; d <<= 1) cnt += (unsigned)__shfl_xor((int)cnt, d);
      if (cnt >= KTOP) lo2 = mid; else hi2 = mid - 1u;
    }
    const unsigned lolo = lo2 * 0x10001u;
    float s2sum = 0.f;
    float exf[32];
#pragma unroll
    for (int j = 0; j < 16; ++j) {
      const unsigned ge = kg[j] - lolo;
      const float aA = (ge & 0x8000u) ? __uint_as_float(pk2[j] << 16) : 0.f;
      const float aB = (ge & 0x80000000u) ? __uint_as_float(pk2[j] & 0xFFFF0000u) : 0.f;
      const float eA = EXP2F(aA * LOG2E);
      const float eB = EXP2F(aB * LOG2E);
      exf[2 * j] = eA; exf[2 * j + 1] = eB;
      s2sum += eA + eB;
    }
#pragma unroll
    for (int d = 1; d < 64; d <<= 1) s2sum += __shfl_xor(s2sum, d);
    const float inv = 1.f / s2sum;
#pragma unroll
    for (int k = 0; k < 8; ++k) {
      float4 o;
      o.x = exf[4 * k + 0] * inv; o.y = exf[4 * k + 1] * inv;
      o.z = exf[4 * k + 2] * inv; o.w = exf[4 * k + 3] * inv;
      *(float4*)(op + 4 * lane + 256 * k) = o;
    }
  }
}

extern "C" void kernel_launch(void* const* d_in, const int* in_sizes, int n_in,
                              void* d_out, int out_size, void* d_ws, size_t ws_size,
                              hipStream_t stream) {
  const float* x   = (const float*)d_in[0];
  const float* mem = (const float*)d_in[1];
  const float* fcw = (const float*)d_in[2];
  const float* fcb = (const float*)d_in[3];
  float* out = (float*)d_out;
  unsigned short* xsH  = (unsigned short*)d_ws;             // 2 MB
  unsigned short* xsL  = xsH + (size_t)B_ * N_ * C_;        // 2 MB
  unsigned short* memT = xsL + (size_t)B_ * N_ * C_;        // 128 KB

  dim3 g1(N_ / 64, B_);
  prep_kernel<<<g1, 256, 0, stream>>>(x, mem, xsH, xsL, memT);
  dim3 g2(N_ / 16, B_);
  adj_kernel<<<g2, 1024, 0, stream>>>(xsH, xsL, memT, fcw, fcb, out);
}

// Round 15
// 131.723 us; speedup vs baseline: 1.0793x; 1.0334x over previous
//
#include <hip/hip_runtime.h>
#include <hip/hip_bf16.h>
#include <cstdint>
#include <cstddef>

#define B_ 16
#define N_ 2048
#define L_ 12
#define C_ 32
#define KTOP 1638
#define SCALE 0.17677669529663687f   // 1/sqrt(32)
#define LOG2E 1.44269504088896f

typedef __attribute__((ext_vector_type(8))) short short8v;
typedef __attribute__((ext_vector_type(4))) float f32x4;

#if __has_builtin(__builtin_amdgcn_exp2f)
#define EXP2F(x) __builtin_amdgcn_exp2f(x)
#else
#define EXP2F(x) exp2f(x)
#endif

__device__ __forceinline__ unsigned short bf16_rne(float v) {
  unsigned u = __float_as_uint(v);
  u += 0x7FFFu + ((u >> 16) & 1u);
  return (unsigned short)(u >> 16);
}
// exp(x) quartic for x in [0, 0.72]: abs err <= ~1.6e-3 (x^5/120)
__device__ __forceinline__ float exp_poly4(float x) {
  return fmaf(x, fmaf(x, fmaf(x, fmaf(x, 0.041666667f, 0.166666667f), 0.5f), 1.f), 1.f);
}

// Kernel 1: xsum split into bf16 hi/lo, layout [b][n][c]; blocks with b==0
// also convert mem -> bf16 memT [m][c], PRE-SCALED by K=SCALE*LOG2E so
// phase A computes p1 = exp2(max(acc1,0)) directly (tie class unaffected:
// acc1<=0 -> p1=1 exactly).
__global__ __launch_bounds__(256) void prep_kernel(const float* __restrict__ x,
                                                   const float* __restrict__ mem,
                                                   unsigned short* __restrict__ xsH,
                                                   unsigned short* __restrict__ xsL,
                                                   unsigned short* __restrict__ memT) {
  const int b = blockIdx.y, n0 = blockIdx.x * 64;
  const int c = threadIdx.x & 31, nr = threadIdx.x >> 5;
#pragma unroll
  for (int i = 0; i < 8; ++i) {
    const int n = n0 + i * 8 + nr;
    const float* px = x + ((size_t)(b * N_ + n) * L_) * C_ + c;
    float s = 0.f;
#pragma unroll
    for (int l = 0; l < L_; ++l) s += px[l * C_];
    const unsigned short h = bf16_rne(s);
    const float hf = __uint_as_float((unsigned)h << 16);
    const unsigned short lo = bf16_rne(s - hf);
    const size_t o = (size_t)(b * N_ + n) * C_ + c;
    xsH[o] = h;
    xsL[o] = lo;
  }
  if (b == 0) {
    const float KF = SCALE * LOG2E;
#pragma unroll
    for (int i = 0; i < 8; ++i) {
      const int idx = i * 256 + threadIdx.x;
      const int ml = idx >> 5, cc = idx & 31;
      memT[(size_t)(n0 + ml) * C_ + cc] = bf16_rne(mem[(size_t)cc * N_ + n0 + ml] * KF);
    }
  }
}

// Kernel 2: R12 structure (best measured) — one block = 8 rows, 512 threads
// (8 waves), u32 pbuf (64 KB), 2 blocks/CU.
// Phase A: MFMA 16x16x32, permuted A-row padding, max-free softmaxes,
// p1/p2 cvt_pk'd to pbuf. Phase B: f32-native fused pass — adj in f32,
// tie-anchor T bit-exact, counts + masked quartic-exp + bf16-packed exp regs
// in ONE pass; fast path self-verified by counts; bf16-key binary search as
// the rare wave-local fallback (no barrier inside).
__global__ __launch_bounds__(512, 4) void adj_kernel(
    const unsigned short* __restrict__ xsH, const unsigned short* __restrict__ xsL,
    const unsigned short* __restrict__ memT, const float* __restrict__ fc_w,
    const float* __restrict__ fc_b, float* __restrict__ out) {
  __shared__ unsigned pbuf[8][2049];      // +1 pad
  __shared__ float red1[8][8], red2[8][8];

  const int tid = threadIdx.x, wid = tid >> 6, lane = tid & 63;
  const int l15 = lane & 15, g = lane >> 4;
  const int b = blockIdx.y, n0 = blockIdx.x * 8;

  // Permuted A rows: lane group g's C components {0,1} are logical rows
  // {rbase, rbase+1}, rbase = {0,4,2,6}[g].
  const int fr = (l15 < 8) ? l15 : ((l15 - 6) & 7);
  const int rbase = (g & 1) * 4 + (g & 2);
  const int g8 = g * 8;
  const size_t arow = (size_t)(b * N_ + n0 + fr) * C_ + g8;
  const short8v hiA = *(const short8v*)(xsH + arow);
  const short8v loFA = *(const short8v*)(xsL + arow);

  const f32x4 zero = {0.f, 0.f, 0.f, 0.f};
  const float K = SCALE * LOG2E;
  const float C2 = -80.f * LOG2E;
  const int mbase = wid * 256 + l15;
  const size_t bcol = (size_t)b * N_ * C_ + (size_t)mbase * C_ + g8;
  const unsigned short* pH = xsH + bcol;
  const unsigned short* pL = xsL + bcol;
  const unsigned short* pM = memT + (size_t)mbase * C_ + g8;
  unsigned* pw = &pbuf[rbase][mbase];

  float s1[2] = {0.f, 0.f}, s2[2] = {0.f, 0.f};

#pragma unroll
  for (int t = 0; t < 16; ++t) {
    const short8v hiB = *(const short8v*)(pH + t * (16 * C_));
    const short8v loB = *(const short8v*)(pL + t * (16 * C_));
    const short8v mB  = *(const short8v*)(pM + t * (16 * C_));

    f32x4 acc1 = __builtin_amdgcn_mfma_f32_16x16x32_bf16(hiA, mB, zero, 0, 0, 0);
    f32x4 acc2 = __builtin_amdgcn_mfma_f32_16x16x32_bf16(hiA, hiB, zero, 0, 0, 0);
    acc2 = __builtin_amdgcn_mfma_f32_16x16x32_bf16(hiA, loB, acc2, 0, 0, 0);
    acc2 = __builtin_amdgcn_mfma_f32_16x16x32_bf16(loFA, hiB, acc2, 0, 0, 0);

#pragma unroll
    for (int s = 0; s < 2; ++s) {
      const float p1 = EXP2F(fmaxf(acc1[s], 0.f));                       // memT pre-scaled
      const float p2 = EXP2F(fminf(fmaf(fmaxf(acc2[s], 0.f), K, C2), 127.f));
      s1[s] += p1; s2[s] += p2;
      union { __hip_bfloat162 h2; unsigned u; } pk;
      pk.h2 = __float22bfloat162_rn(float2{p1, p2});
      pw[s * 2049 + t * 16] = pk.u;
    }
  }

#pragma unroll
  for (int d = 1; d < 16; d <<= 1) {
#pragma unroll
    for (int s = 0; s < 2; ++s) {
      s1[s] += __shfl_xor(s1[s], d);
      s2[s] += __shfl_xor(s2[s], d);
    }
  }
  if (l15 == 0) {
#pragma unroll
    for (int s = 0; s < 2; ++s) {
      red1[wid][rbase + s] = s1[s];
      red2[wid][rbase + s] = s2[s];
    }
  }
  __syncthreads();

  // ---- Phase B: wave wid owns row wid; lane owns cols {4*lane+256k} ----
  const int r = wid;
  float S1 = 0.f, S2 = 0.f;
#pragma unroll
  for (int w = 0; w < 8; ++w) { S1 += red1[w][r]; S2 += red2[w][r]; }
  const float w0 = fc_w[0], w1 = fc_w[1], bb = fc_b[0];
  const float i1 = w0 / S1, i2 = w1 / S2;
  const unsigned* prow = &pbuf[0][0] + r * 2049;

  // Tie value T, bit-exact vs the per-element adj computation below.
  const float p2t = __uint_as_float((unsigned)bf16_rne(EXP2F(C2)) << 16);
  const float T = fmaf(p2t, i2, fmaf(1.0f, i1, bb));

  // Fused pass: adj (f32), counts vs T, masked quartic exp, bf16-pack.
  unsigned exb[16];          // packed bf16 exp pairs
  float ssum = 0.f;
  unsigned cge = 0, cgt = 0;
#pragma unroll
  for (int k = 0; k < 8; ++k) {
    const uint4 q = *(const uint4*)&prow[4 * lane + 256 * k];
    const unsigned qq[4] = {q.x, q.y, q.z, q.w};
    float e4[4];
#pragma unroll
    for (int c4 = 0; c4 < 4; ++c4) {
      const float p1 = __uint_as_float(qq[c4] << 16);
      const float p2 = __uint_as_float(qq[c4] & 0xFFFF0000u);
      const float adj = fmaf(p2, i2, fmaf(p1, i1, bb));
      cge += (adj >= T) ? 1u : 0u;
      cgt += (adj >  T) ? 1u : 0u;
      const float am = (adj >= T) ? adj : 0.f;
      const float e = exp_poly4(am);
      e4[c4] = e;
      ssum += e;
    }
    union { __hip_bfloat162 h2; unsigned u; } pa, pb2;
    pa.h2  = __float22bfloat162_rn(float2{e4[0], e4[1]});
    pb2.h2 = __float22bfloat162_rn(float2{e4[2], e4[3]});
    exb[2 * k] = pa.u; exb[2 * k + 1] = pb2.u;
  }
  unsigned comb = cge | (cgt << 16);
#pragma unroll
  for (int d = 1; d < 64; d <<= 1) {
    comb += (unsigned)__shfl_xor((int)comb, d);
    ssum += __shfl_xor(ssum, d);
  }
  const unsigned CGE = comb & 0xFFFFu, CGT = comb >> 16;

  float* op = out + ((size_t)(b * N_ + n0 + r)) * N_;

  if (CGE >= KTOP && CGT < KTOP) {
    // ---- fast path (expected always): threshold is T, sum is ssum ----
    const float inv = 1.f / ssum;
#pragma unroll
    for (int k = 0; k < 8; ++k) {
      float4 o;
      o.x = __uint_as_float(exb[2 * k] << 16) * inv;
      o.y = __uint_as_float(exb[2 * k] & 0xFFFF0000u) * inv;
      o.z = __uint_as_float(exb[2 * k + 1] << 16) * inv;
      o.w = __uint_as_float(exb[2 * k + 1] & 0xFFFF0000u) * inv;
      *(float4*)(op + 4 * lane + 256 * k) = o;
    }
  } else {
    // ---- rare fallback: bf16-key binary search (wave-local, no barriers) ----
    unsigned pk2[16], kg[16];
#pragma unroll
    for (int k = 0; k < 8; ++k) {
      const uint4 q = *(const uint4*)&prow[4 * lane + 256 * k];
      const unsigned qq[4] = {q.x, q.y, q.z, q.w};
      float a4[4];
#pragma unroll
      for (int c4 = 0; c4 < 4; ++c4) {
        const float p1 = __uint_as_float(qq[c4] << 16);
        const float p2 = __uint_as_float(qq[c4] & 0xFFFF0000u);
        a4[c4] = fmaf(p2, i2, fmaf(p1, i1, bb));
      }
      union { __hip_bfloat162 h2; unsigned u; } cA, cB;
      cA.h2 = __float22bfloat162_rn(float2{a4[0], a4[1]});
      cB.h2 = __float22bfloat162_rn(float2{a4[2], a4[3]});
      pk2[2 * k] = cA.u; pk2[2 * k + 1] = cB.u;
      unsigned sgn = (cA.u >> 15) & 0x00010001u;
      unsigned srt = cA.u ^ 0x80008000u ^ (sgn * 0x7FFFu);
      kg[2 * k] = ((srt >> 1) & 0x7FFF7FFFu) | 0x80008000u;
      sgn = (pk2[2 * k + 1] >> 15) & 0x00010001u;
      srt = pk2[2 * k + 1] ^ 0x80008000u ^ (sgn * 0x7FFFu);
      kg[2 * k + 1] = ((srt >> 1) & 0x7FFF7FFFu) | 0x80008000u;
    }
    unsigned mn = 0x7FFFu, mx = 0u;
#pragma unroll
    for (int j = 0; j < 16; ++j) {
      const unsigned k15 = kg[j] & 0x7FFF7FFFu;
      mn = min(mn, min(k15 & 0xFFFFu, k15 >> 16));
      mx = max(mx, max(k15 & 0xFFFFu, k15 >> 16));
    }
#pragma unroll
    for (int d = 1; d < 64; d <<= 1) {
      mn = min(mn, (unsigned)__shfl_xor((int)mn, d));
      mx = max(mx, (unsigned)__shfl_xor((int)mx, d));
    }
    unsigned lo2 = mn, hi2 = mx;
#pragma unroll 1
    for (int it = 0; it < 15; ++it) {
      if (lo2 >= hi2) break;
      const unsigned mid = (lo2 + hi2 + 1u) >> 1;
      const unsigned mm = mid * 0x10001u;
      unsigned c0 = 0;
#pragma unroll
      for (int j = 0; j < 16; ++j) c0 += ((kg[j] - mm) >> 15) & 0x10001u;
      unsigned cnt = (c0 & 0xFFFFu) + (c0 >> 16);
#pragma unroll
      for (int d = 1; d < 64; d <<= 1) cnt += (unsigned)__shfl_xor((int)cnt, d);
      if (cnt >= KTOP) lo2 = mid; else hi2 = mid - 1u;
    }
    const unsigned lolo = lo2 * 0x10001u;
    float s2sum = 0.f;
    float exf[32];
#pragma unroll
    for (int j = 0; j < 16; ++j) {
      const unsigned ge = kg[j] - lolo;
      const float aA = (ge & 0x8000u) ? __uint_as_float(pk2[j] << 16) : 0.f;
      const float aB = (ge & 0x80000000u) ? __uint_as_float(pk2[j] & 0xFFFF0000u) : 0.f;
      const float eA = EXP2F(aA * LOG2E);
      const float eB = EXP2F(aB * LOG2E);
      exf[2 * j] = eA; exf[2 * j + 1] = eB;
      s2sum += eA + eB;
    }
#pragma unroll
    for (int d = 1; d < 64; d <<= 1) s2sum += __shfl_xor(s2sum, d);
    const float inv = 1.f / s2sum;
#pragma unroll
    for (int k = 0; k < 8; ++k) {
      float4 o;
      o.x = exf[4 * k + 0] * inv; o.y = exf[4 * k + 1] * inv;
      o.z = exf[4 * k + 2] * inv; o.w = exf[4 * k + 3] * inv;
      *(float4*)(op + 4 * lane + 256 * k) = o;
    }
  }
}

extern "C" void kernel_launch(void* const* d_in, const int* in_sizes, int n_in,
                              void* d_out, int out_size, void* d_ws, size_t ws_size,
                              hipStream_t stream) {
  const float* x   = (const float*)d_in[0];
  const float* mem = (const float*)d_in[1];
  const float* fcw = (const float*)d_in[2];
  const float* fcb = (const float*)d_in[3];
  float* out = (float*)d_out;
  unsigned short* xsH  = (unsigned short*)d_ws;             // 2 MB
  unsigned short* xsL  = xsH + (size_t)B_ * N_ * C_;        // 2 MB
  unsigned short* memT = xsL + (size_t)B_ * N_ * C_;        // 128 KB

  dim3 g1(N_ / 64, B_);
  prep_kernel<<<g1, 256, 0, stream>>>(x, mem, xsH, xsL, memT);
  dim3 g2(N_ / 8, B_);
  adj_kernel<<<g2, 512, 0, stream>>>(xsH, xsL, memT, fcw, fcb, out);
}